// Round 6
// baseline (1699.896 us; speedup 1.0000x reference)
//
#include <hip/hip_runtime.h>

#define BN_EPS 1e-5f
#define CHUNK 8192
#define MAXB 1024   // max buckets (N up to 131072 with 128 nodes/bucket)
#define BSH 7       // 128 nodes per bucket
#define BNODES 128

// bf16 helpers (RNE pack, cheap unpack)
__device__ __forceinline__ unsigned short f2bf(float f) {
    unsigned int u = __float_as_uint(f);
    u += 0x7FFF + ((u >> 16) & 1);
    return (unsigned short)(u >> 16);
}
__device__ __forceinline__ float bf2f(unsigned short h) {
    return __uint_as_float((unsigned int)h << 16);
}

// ---------------- bucket build: group edges by dst>>7, no per-node CSR ----------------

__global__ __launch_bounds__(256) void bin_count(const int* __restrict__ ei, int E,
                                                 int* __restrict__ bcnt, int nbuck) {
    __shared__ int h[MAXB];
    for (int i = threadIdx.x; i < nbuck; i += 256) h[i] = 0;
    __syncthreads();
    int i = blockIdx.x * 256 + threadIdx.x, stride = gridDim.x * 256;
    for (int e = i; e < E; e += stride) {
        int d = ei[E + e];
        atomicAdd(&h[d >> BSH], 1);
    }
    __syncthreads();
    for (int b = threadIdx.x; b < nbuck; b += 256)
        if (h[b]) atomicAdd(&bcnt[b], h[b]);
}

// single block, 1024 threads: exclusive scan of bcnt[0..nbuck) -> boff & bpos
__global__ __launch_bounds__(1024) void scan_small(const int* __restrict__ bcnt,
                                                   int* __restrict__ boff,
                                                   int* __restrict__ bpos,
                                                   int nbuck, int E) {
    __shared__ int wsum[16];
    int tid = threadIdx.x, lane = tid & 63, wv = tid >> 6;
    int val = (tid < nbuck) ? bcnt[tid] : 0;
    int s = val;
#pragma unroll
    for (int off = 1; off < 64; off <<= 1) {
        int t = __shfl_up(s, off, 64);
        if (lane >= off) s += t;
    }
    if (lane == 63) wsum[wv] = s;
    __syncthreads();
    if (wv == 0) {
        int t = (lane < 16) ? wsum[lane] : 0;
#pragma unroll
        for (int off = 1; off < 16; off <<= 1) {
            int u = __shfl_up(t, off, 64);
            if (lane >= off) t += u;
        }
        if (lane < 16) wsum[lane] = t;
    }
    __syncthreads();
    int excl = ((wv == 0) ? 0 : wsum[wv - 1]) + s - val;
    if (tid < nbuck) { boff[tid] = excl; bpos[tid] = excl; }
    if (tid == 0) boff[nbuck] = E;
}

// 8K-edge chunks, 196 blocks (R4-proven): LDS hist -> reserve -> ranked packed write
__global__ __launch_bounds__(256) void bin_scatter(const int* __restrict__ ei, int E,
                                                   int* __restrict__ bpos,
                                                   int* __restrict__ binned, int nbuck) {
    __shared__ int h[MAXB];
    __shared__ int res[MAXB];
    int base = blockIdx.x * CHUNK;
    int cnt = min(CHUNK, E - base);
    int tid = threadIdx.x;
    for (int b = tid; b < nbuck; b += 256) h[b] = 0;
    __syncthreads();
    for (int k = tid; k < cnt; k += 256) {
        int d = ei[E + base + k];
        atomicAdd(&h[d >> BSH], 1);
    }
    __syncthreads();
    for (int b = tid; b < nbuck; b += 256) {
        int c = h[b];
        res[b] = c ? atomicAdd(&bpos[b], c) : 0;
        h[b] = 0;  // reuse as rank counter
    }
    __syncthreads();
    for (int k = tid; k < cnt; k += 256) {
        int srcv = ei[base + k];
        int d = ei[E + base + k];
        int b = d >> BSH;
        int r = atomicAdd(&h[b], 1);
        binned[res[b] + r] = ((d & (BNODES - 1)) << 17) | srcv;  // src < 2^17
    }
}

// ---------------- dense: Y[n][64](bf16) = X[n][K](f32) @ W[64][K]^T ----------------
template <int K>
__global__ __launch_bounds__(256) void linear_kernel(const float* __restrict__ X,
                                                     const float* __restrict__ W,
                                                     unsigned short* __restrict__ Y, int N) {
    __shared__ float wlds[K * 64];
    __shared__ float xlds[16 * K];
    int tid = threadIdx.x;
    for (int j = tid; j < 64 * K; j += 256) {
        int o = j / K, k = j % K;
        wlds[(k >> 2) * 256 + o * 4 + (k & 3)] = W[j];
    }
    __syncthreads();
    const float4* w4p = (const float4*)wlds;
    const float4* x4p = (const float4*)xlds;
    int wv = tid >> 6, lane = tid & 63;
    for (int nb = blockIdx.x * 16; nb < N; nb += gridDim.x * 16) {
        const float4* xg = (const float4*)(X + (size_t)nb * K);
        float4* xl = (float4*)xlds;
        for (int j = tid; j < 16 * K / 4; j += 256) xl[j] = xg[j];
        __syncthreads();
        int r = wv * 4;
        float a0 = 0.f, a1 = 0.f, a2 = 0.f, a3 = 0.f;
#pragma unroll 8
        for (int kb = 0; kb < K / 4; kb++) {
            float4 w = w4p[kb * 64 + lane];
            float4 x0 = x4p[(r + 0) * (K / 4) + kb];
            float4 x1 = x4p[(r + 1) * (K / 4) + kb];
            float4 x2 = x4p[(r + 2) * (K / 4) + kb];
            float4 x3 = x4p[(r + 3) * (K / 4) + kb];
            a0 += x0.x * w.x + x0.y * w.y + x0.z * w.z + x0.w * w.w;
            a1 += x1.x * w.x + x1.y * w.y + x1.z * w.z + x1.w * w.w;
            a2 += x2.x * w.x + x2.y * w.y + x2.z * w.z + x2.w * w.w;
            a3 += x3.x * w.x + x3.y * w.y + x3.z * w.z + x3.w * w.w;
        }
        Y[(size_t)(nb + r + 0) * 64 + lane] = f2bf(a0);
        Y[(size_t)(nb + r + 1) * 64 + lane] = f2bf(a1);
        Y[(size_t)(nb + r + 2) * 64 + lane] = f2bf(a2);
        Y[(size_t)(nb + r + 3) * 64 + lane] = f2bf(a3);
        __syncthreads();
    }
}

// ---------------- gather2: per-bucket LDS accumulation ----------------
// T[i] = relu(Y[i] + bias + sum_{e: dst(e)=i} Y[src(e)]), bucket = 128 nodes
__global__ __launch_bounds__(256) void gather2(const unsigned short* __restrict__ Y,
                                               const int* __restrict__ boff,
                                               const int* __restrict__ binned,
                                               const float* __restrict__ bias,
                                               unsigned short* __restrict__ T, int N) {
    __shared__ float acc[BNODES * 64];  // 32 KB -> 5 blocks/CU
    int b = blockIdx.x, tid = threadIdx.x, lane = tid & 63, wv = tid >> 6;
    float4* a4 = (float4*)acc;
#pragma unroll
    for (int i = tid; i < BNODES * 16; i += 256) a4[i] = make_float4(0.f, 0.f, 0.f, 0.f);
    float bl = bias[lane];
    __syncthreads();
    int lo = boff[b], hi = boff[b + 1];
    int e = lo + wv;
    for (; e + 28 < hi; e += 32) {  // 4 waves interleaved, unroll 8
        int v0 = binned[e], v1 = binned[e + 4], v2 = binned[e + 8], v3 = binned[e + 12];
        int v4 = binned[e + 16], v5 = binned[e + 20], v6 = binned[e + 24], v7 = binned[e + 28];
        float f0 = bf2f(Y[(size_t)(v0 & 0x1FFFF) * 64 + lane]);
        float f1 = bf2f(Y[(size_t)(v1 & 0x1FFFF) * 64 + lane]);
        float f2 = bf2f(Y[(size_t)(v2 & 0x1FFFF) * 64 + lane]);
        float f3 = bf2f(Y[(size_t)(v3 & 0x1FFFF) * 64 + lane]);
        float f4 = bf2f(Y[(size_t)(v4 & 0x1FFFF) * 64 + lane]);
        float f5 = bf2f(Y[(size_t)(v5 & 0x1FFFF) * 64 + lane]);
        float f6 = bf2f(Y[(size_t)(v6 & 0x1FFFF) * 64 + lane]);
        float f7 = bf2f(Y[(size_t)(v7 & 0x1FFFF) * 64 + lane]);
        atomicAdd(&acc[(v0 >> 17) * 64 + lane], f0);
        atomicAdd(&acc[(v1 >> 17) * 64 + lane], f1);
        atomicAdd(&acc[(v2 >> 17) * 64 + lane], f2);
        atomicAdd(&acc[(v3 >> 17) * 64 + lane], f3);
        atomicAdd(&acc[(v4 >> 17) * 64 + lane], f4);
        atomicAdd(&acc[(v5 >> 17) * 64 + lane], f5);
        atomicAdd(&acc[(v6 >> 17) * 64 + lane], f6);
        atomicAdd(&acc[(v7 >> 17) * 64 + lane], f7);
    }
    for (; e < hi; e += 4) {
        int v = binned[e];
        atomicAdd(&acc[(v >> 17) * 64 + lane], bf2f(Y[(size_t)(v & 0x1FFFF) * 64 + lane]));
    }
    __syncthreads();
    int base = b << BSH;
    for (int n = wv; n < BNODES; n += 4) {
        int node = base + n;
        if (node >= N) break;
        float r = acc[n * 64 + lane] + bf2f(Y[(size_t)node * 64 + lane]) + bl;
        __builtin_nontemporal_store(f2bf(fmaxf(r, 0.f)), &T[(size_t)node * 64 + lane]);
    }
}

// stage 16 nodes x 64 feats of bf16 into f32 LDS tile
__device__ __forceinline__ void stage_bf16_tile(const unsigned short* __restrict__ src,
                                                float* __restrict__ dst, int tid) {
    const ushort4* s4 = (const ushort4*)src;
    ushort4 u = s4[tid];  // 256 threads x 4 elems = 1024
    float4* d4 = (float4*)dst;
    d4[tid] = make_float4(bf2f(u.x), bf2f(u.y), bf2f(u.z), bf2f(u.w));
}

// ---------------- fused: Y(bf16) = (relu(bn(T@W1^T + b1))) @ W2^T ----------------
__global__ __launch_bounds__(256) void fused_mlp2_kernel(
    const unsigned short* __restrict__ T, const float* __restrict__ W1,
    const float* __restrict__ b1, const float* __restrict__ g, const float* __restrict__ be,
    const float* __restrict__ m, const float* __restrict__ v, const float* __restrict__ W2,
    unsigned short* __restrict__ Y, int N) {
    __shared__ float w1lds[64 * 64];
    __shared__ float w2lds[64 * 64];
    __shared__ float tl[16 * 64];
    __shared__ float hl[16 * 64];
    int tid = threadIdx.x, wv = tid >> 6, lane = tid & 63;
    for (int j = tid; j < 4096; j += 256) {
        int o = j >> 6, k = j & 63;
        int idx = (k >> 2) * 256 + o * 4 + (k & 3);
        w1lds[idx] = W1[j];
        w2lds[idx] = W2[j];
    }
    float bias = b1[lane];
    float s = g[lane] * rsqrtf(v[lane] + BN_EPS);
    float c = be[lane] - m[lane] * s;
    __syncthreads();
    const float4* w14 = (const float4*)w1lds;
    const float4* w24 = (const float4*)w2lds;
    const float4* t4 = (const float4*)tl;
    const float4* h4 = (const float4*)hl;
    for (int nb = blockIdx.x * 16; nb < N; nb += gridDim.x * 16) {
        stage_bf16_tile(T + (size_t)nb * 64, tl, tid);
        __syncthreads();
        int r = wv * 4;
        float a0 = bias, a1 = bias, a2 = bias, a3 = bias;
#pragma unroll
        for (int kb = 0; kb < 16; kb++) {
            float4 w = w14[kb * 64 + lane];
            float4 x0 = t4[(r + 0) * 16 + kb];
            float4 x1 = t4[(r + 1) * 16 + kb];
            float4 x2 = t4[(r + 2) * 16 + kb];
            float4 x3 = t4[(r + 3) * 16 + kb];
            a0 += x0.x * w.x + x0.y * w.y + x0.z * w.z + x0.w * w.w;
            a1 += x1.x * w.x + x1.y * w.y + x1.z * w.z + x1.w * w.w;
            a2 += x2.x * w.x + x2.y * w.y + x2.z * w.z + x2.w * w.w;
            a3 += x3.x * w.x + x3.y * w.y + x3.z * w.z + x3.w * w.w;
        }
        a0 = fmaxf(a0 * s + c, 0.f);
        a1 = fmaxf(a1 * s + c, 0.f);
        a2 = fmaxf(a2 * s + c, 0.f);
        a3 = fmaxf(a3 * s + c, 0.f);
        hl[(r + 0) * 64 + lane] = a0;
        hl[(r + 1) * 64 + lane] = a1;
        hl[(r + 2) * 64 + lane] = a2;
        hl[(r + 3) * 64 + lane] = a3;
        __syncthreads();
        float o0 = 0.f, o1 = 0.f, o2 = 0.f, o3 = 0.f;
#pragma unroll
        for (int kb = 0; kb < 16; kb++) {
            float4 w = w24[kb * 64 + lane];
            float4 x0 = h4[(r + 0) * 16 + kb];
            float4 x1 = h4[(r + 1) * 16 + kb];
            float4 x2 = h4[(r + 2) * 16 + kb];
            float4 x3 = h4[(r + 3) * 16 + kb];
            o0 += x0.x * w.x + x0.y * w.y + x0.z * w.z + x0.w * w.w;
            o1 += x1.x * w.x + x1.y * w.y + x1.z * w.z + x1.w * w.w;
            o2 += x2.x * w.x + x2.y * w.y + x2.z * w.z + x2.w * w.w;
            o3 += x3.x * w.x + x3.y * w.y + x3.z * w.z + x3.w * w.w;
        }
        Y[(size_t)(nb + r + 0) * 64 + lane] = f2bf(o0);
        Y[(size_t)(nb + r + 1) * 64 + lane] = f2bf(o1);
        Y[(size_t)(nb + r + 2) * 64 + lane] = f2bf(o2);
        Y[(size_t)(nb + r + 3) * 64 + lane] = f2bf(o3);
        __syncthreads();
    }
}

// ---------------- H(bf16) = relu(bn(T@W^T + b)) ----------------
__global__ __launch_bounds__(256) void fused_mlp1_kernel(
    const unsigned short* __restrict__ T, const float* __restrict__ W,
    const float* __restrict__ b, const float* __restrict__ g, const float* __restrict__ be,
    const float* __restrict__ m, const float* __restrict__ v,
    unsigned short* __restrict__ H, int N) {
    __shared__ float wlds[64 * 64];
    __shared__ float tl[16 * 64];
    int tid = threadIdx.x, wv = tid >> 6, lane = tid & 63;
    for (int j = tid; j < 4096; j += 256) {
        int o = j >> 6, k = j & 63;
        wlds[(k >> 2) * 256 + o * 4 + (k & 3)] = W[j];
    }
    float bias = b[lane];
    float s = g[lane] * rsqrtf(v[lane] + BN_EPS);
    float c = be[lane] - m[lane] * s;
    __syncthreads();
    const float4* w4 = (const float4*)wlds;
    const float4* t4 = (const float4*)tl;
    for (int nb = blockIdx.x * 16; nb < N; nb += gridDim.x * 16) {
        stage_bf16_tile(T + (size_t)nb * 64, tl, tid);
        __syncthreads();
        int r = wv * 4;
        float a0 = bias, a1 = bias, a2 = bias, a3 = bias;
#pragma unroll
        for (int kb = 0; kb < 16; kb++) {
            float4 w = w4[kb * 64 + lane];
            float4 x0 = t4[(r + 0) * 16 + kb];
            float4 x1 = t4[(r + 1) * 16 + kb];
            float4 x2 = t4[(r + 2) * 16 + kb];
            float4 x3 = t4[(r + 3) * 16 + kb];
            a0 += x0.x * w.x + x0.y * w.y + x0.z * w.z + x0.w * w.w;
            a1 += x1.x * w.x + x1.y * w.y + x1.z * w.z + x1.w * w.w;
            a2 += x2.x * w.x + x2.y * w.y + x2.z * w.z + x2.w * w.w;
            a3 += x3.x * w.x + x3.y * w.y + x3.z * w.z + x3.w * w.w;
        }
        H[(size_t)(nb + r + 0) * 64 + lane] = f2bf(fmaxf(a0 * s + c, 0.f));
        H[(size_t)(nb + r + 1) * 64 + lane] = f2bf(fmaxf(a1 * s + c, 0.f));
        H[(size_t)(nb + r + 2) * 64 + lane] = f2bf(fmaxf(a2 * s + c, 0.f));
        H[(size_t)(nb + r + 3) * 64 + lane] = f2bf(fmaxf(a3 * s + c, 0.f));
        __syncthreads();
    }
}

// ---------------- mean pool per graph (batch is sorted) ----------------
__global__ __launch_bounds__(256) void pool_kernel(const unsigned short* __restrict__ H,
                                                   const int* __restrict__ batch,
                                                   float* __restrict__ out, int N) {
    __shared__ float part[4][64];
    int g = blockIdx.x;
    int tid = threadIdx.x, wv = tid >> 6, lane = tid & 63;
    int lo = 0, hi = N;
    while (lo < hi) { int mid = (lo + hi) >> 1; if (batch[mid] < g) lo = mid + 1; else hi = mid; }
    int start = lo;
    hi = N;
    while (lo < hi) { int mid = (lo + hi) >> 1; if (batch[mid] < g + 1) lo = mid + 1; else hi = mid; }
    int end = lo;
    float acc = 0.f;
    for (int i = start + wv; i < end; i += 4) acc += bf2f(H[(size_t)i * 64 + lane]);
    part[wv][lane] = acc;
    __syncthreads();
    if (tid < 64) {
        float sfin = part[0][tid] + part[1][tid] + part[2][tid] + part[3][tid];
        float cnt = (float)(end - start);
        out[(size_t)g * 64 + tid] = sfin / fmaxf(cnt, 1.f);
    }
}

extern "C" void kernel_launch(void* const* d_in, const int* in_sizes, int n_in,
                              void* d_out, int out_size, void* d_ws, size_t ws_size,
                              hipStream_t stream) {
    const float* x   = (const float*)d_in[0];
    const int*   ei  = (const int*)d_in[1];
    const int*   bat = (const int*)d_in[2];
    const float* W1a = (const float*)d_in[3];
    const float* b1a = (const float*)d_in[4];
    const float* W1b = (const float*)d_in[5];
    const float* b1b = (const float*)d_in[6];
    const float* g1  = (const float*)d_in[7];
    const float* be1 = (const float*)d_in[8];
    const float* m1  = (const float*)d_in[9];
    const float* v1  = (const float*)d_in[10];
    const float* W2a = (const float*)d_in[11];
    const float* b2a = (const float*)d_in[12];
    const float* W2b = (const float*)d_in[13];
    const float* b2b = (const float*)d_in[14];
    const float* g2  = (const float*)d_in[15];
    const float* be2 = (const float*)d_in[16];
    const float* m2  = (const float*)d_in[17];
    const float* v2  = (const float*)d_in[18];
    float* out = (float*)d_out;

    int N = in_sizes[0] / 128;
    int E = in_sizes[1] / 2;
    int G = out_size / 64;
    int nbuck = (N + BNODES - 1) >> BSH;
    int ntile = (N + 15) / 16;

    // workspace layout
    char* ws = (char*)d_ws;
    int* bcnt = (int*)ws;                                 // MAXB
    int* boff = bcnt + MAXB;                              // MAXB+4
    int* bpos = boff + MAXB + 4;                          // MAXB
    int* binned = bpos + MAXB;                            // E (persists across both gathers)
    unsigned short* bufA = (unsigned short*)(binned + E); // N*64 bf16
    unsigned short* bufB = bufA + (size_t)N * 64;         // N*64 bf16

    // bucket build
    hipMemsetAsync(bcnt, 0, MAXB * sizeof(int), stream);
    bin_count<<<512, 256, 0, stream>>>(ei, E, bcnt, nbuck);
    scan_small<<<1, 1024, 0, stream>>>(bcnt, boff, bpos, nbuck, E);
    bin_scatter<<<(E + CHUNK - 1) / CHUNK, 256, 0, stream>>>(ei, E, bpos, binned, nbuck);

    // layer 1
    linear_kernel<128><<<ntile, 256, 0, stream>>>(x, W1a, bufA, N);
    gather2<<<nbuck, 256, 0, stream>>>(bufA, boff, binned, b1a, bufB, N);
    fused_mlp2_kernel<<<ntile, 256, 0, stream>>>(bufB, W1b, b1b, g1, be1, m1, v1, W2a, bufA, N);

    // layer 2
    gather2<<<nbuck, 256, 0, stream>>>(bufA, boff, binned, b2a, bufB, N);
    fused_mlp1_kernel<<<ntile, 256, 0, stream>>>(bufB, W2b, b2b, g2, be2, m2, v2, bufA, N);

    // mean pool
    pool_kernel<<<G, 256, 0, stream>>>(bufA, bat, out, N);
}

// Round 7
// 576.246 us; speedup vs baseline: 2.9499x; 2.9499x over previous
//
#include <hip/hip_runtime.h>

#define BN_EPS 1e-5f
#define CHUNK 8192
#define MAXB 512  // max buckets (N up to 131072 with 256 nodes/bucket)

// bf16 helpers (RNE pack, cheap unpack)
__device__ __forceinline__ unsigned short f2bf(float f) {
    unsigned int u = __float_as_uint(f);
    u += 0x7FFF + ((u >> 16) & 1);
    return (unsigned short)(u >> 16);
}
__device__ __forceinline__ float bf2f(unsigned short h) {
    return __uint_as_float((unsigned int)h << 16);
}

// ---------------- CSR build: bucketed, no global random scatter (R4-proven) ----------------

__global__ __launch_bounds__(256) void bin_count(const int* __restrict__ ei, int E,
                                                 int* __restrict__ bcnt, int nbuck) {
    __shared__ int h[MAXB];
    for (int i = threadIdx.x; i < nbuck; i += 256) h[i] = 0;
    __syncthreads();
    int i = blockIdx.x * 256 + threadIdx.x, stride = gridDim.x * 256;
    for (int e = i; e < E; e += stride) {
        int d = ei[E + e];
        atomicAdd(&h[d >> 8], 1);
    }
    __syncthreads();
    for (int b = threadIdx.x; b < nbuck; b += 256)
        if (h[b]) atomicAdd(&bcnt[b], h[b]);
}

__global__ __launch_bounds__(512) void scan_small(const int* __restrict__ bcnt,
                                                  int* __restrict__ boff,
                                                  int* __restrict__ bpos,
                                                  int* __restrict__ row_ptr_end,
                                                  int nbuck, int E) {
    __shared__ int wsum[8];
    int tid = threadIdx.x, lane = tid & 63, wv = tid >> 6;
    int val = (tid < nbuck) ? bcnt[tid] : 0;
    int s = val;
#pragma unroll
    for (int off = 1; off < 64; off <<= 1) {
        int t = __shfl_up(s, off, 64);
        if (lane >= off) s += t;
    }
    if (lane == 63) wsum[wv] = s;
    __syncthreads();
    if (wv == 0) {
        int t = (lane < 8) ? wsum[lane] : 0;
#pragma unroll
        for (int off = 1; off < 8; off <<= 1) {
            int u = __shfl_up(t, off, 64);
            if (lane >= off) t += u;
        }
        if (lane < 8) wsum[lane] = t;
    }
    __syncthreads();
    int excl = ((wv == 0) ? 0 : wsum[wv - 1]) + s - val;
    if (tid < nbuck) { boff[tid] = excl; bpos[tid] = excl; }
    if (tid == 0) { boff[nbuck] = E; *row_ptr_end = E; }
}

// 8K-edge chunks, 196 blocks (R4-proven sweet spot: write-amp vs occupancy)
__global__ __launch_bounds__(256) void bin_scatter(const int* __restrict__ ei, int E,
                                                   int* __restrict__ bpos,
                                                   int* __restrict__ binned, int nbuck) {
    __shared__ int h[MAXB];
    __shared__ int res[MAXB];
    int base = blockIdx.x * CHUNK;
    int cnt = min(CHUNK, E - base);
    int tid = threadIdx.x;
    for (int b = tid; b < nbuck; b += 256) h[b] = 0;
    __syncthreads();
    for (int k = tid; k < cnt; k += 256) {
        int d = ei[E + base + k];
        atomicAdd(&h[d >> 8], 1);
    }
    __syncthreads();
    for (int b = tid; b < nbuck; b += 256) {
        int c = h[b];
        res[b] = c ? atomicAdd(&bpos[b], c) : 0;
        h[b] = 0;  // reuse as rank counter
    }
    __syncthreads();
    for (int k = tid; k < cnt; k += 256) {
        int srcv = ei[base + k];
        int d = ei[E + base + k];
        int b = d >> 8;
        int r = atomicAdd(&h[b], 1);
        binned[res[b] + r] = ((d & 255) << 17) | srcv;  // src < 2^17
    }
}

// one workgroup (512 thr) per 256-node bucket: counts -> scan -> row_ptr + ranked esrc
__global__ __launch_bounds__(512) void bucket_csr(const int* __restrict__ binned,
                                                  const int* __restrict__ boff,
                                                  int* __restrict__ row_ptr,
                                                  int* __restrict__ esrc, int N) {
    __shared__ int ncnt[256];
    __shared__ int npos[256];
    __shared__ int wsum[4];
    int b = blockIdx.x, tid = threadIdx.x, lane = tid & 63, wv = tid >> 6;
    int lo = boff[b], hi = boff[b + 1];
    int base_node = b << 8;
    if (tid < 256) ncnt[tid] = 0;
    __syncthreads();
    for (int i = lo + tid; i < hi; i += 512)
        atomicAdd(&ncnt[binned[i] >> 17], 1);
    __syncthreads();
    if (tid < 256) {
        int c = ncnt[tid];
        int s = c;
#pragma unroll
        for (int off = 1; off < 64; off <<= 1) {
            int t = __shfl_up(s, off, 64);
            if (lane >= off) s += t;
        }
        if (lane == 63) wsum[wv] = s;
        __syncthreads();
        int woff = 0;
#pragma unroll
        for (int i = 0; i < 4; i++) woff += (i < wv) ? wsum[i] : 0;
        int abspos = lo + woff + (s - c);
        if (base_node + tid < N) row_ptr[base_node + tid] = abspos;
        npos[tid] = abspos;
    } else {
        __syncthreads();
    }
    __syncthreads();
    for (int i = lo + tid; i < hi; i += 512) {
        int val = binned[i];
        int r = atomicAdd(&npos[val >> 17], 1);
        esrc[r] = val & 0x1FFFF;
    }
}

// ---------------- dense: Y[n][64](bf16) = X[n][K](f32) @ W[64][K]^T ----------------
template <int K>
__global__ __launch_bounds__(256) void linear_kernel(const float* __restrict__ X,
                                                     const float* __restrict__ W,
                                                     unsigned short* __restrict__ Y, int N) {
    __shared__ float wlds[K * 64];
    __shared__ float xlds[16 * K];
    int tid = threadIdx.x;
    for (int j = tid; j < 64 * K; j += 256) {
        int o = j / K, k = j % K;
        wlds[(k >> 2) * 256 + o * 4 + (k & 3)] = W[j];
    }
    __syncthreads();
    const float4* w4p = (const float4*)wlds;
    const float4* x4p = (const float4*)xlds;
    int wv = tid >> 6, lane = tid & 63;
    for (int nb = blockIdx.x * 16; nb < N; nb += gridDim.x * 16) {
        const float4* xg = (const float4*)(X + (size_t)nb * K);
        float4* xl = (float4*)xlds;
        for (int j = tid; j < 16 * K / 4; j += 256) xl[j] = xg[j];
        __syncthreads();
        int r = wv * 4;
        float a0 = 0.f, a1 = 0.f, a2 = 0.f, a3 = 0.f;
#pragma unroll 8
        for (int kb = 0; kb < K / 4; kb++) {
            float4 w = w4p[kb * 64 + lane];
            float4 x0 = x4p[(r + 0) * (K / 4) + kb];
            float4 x1 = x4p[(r + 1) * (K / 4) + kb];
            float4 x2 = x4p[(r + 2) * (K / 4) + kb];
            float4 x3 = x4p[(r + 3) * (K / 4) + kb];
            a0 += x0.x * w.x + x0.y * w.y + x0.z * w.z + x0.w * w.w;
            a1 += x1.x * w.x + x1.y * w.y + x1.z * w.z + x1.w * w.w;
            a2 += x2.x * w.x + x2.y * w.y + x2.z * w.z + x2.w * w.w;
            a3 += x3.x * w.x + x3.y * w.y + x3.z * w.z + x3.w * w.w;
        }
        Y[(size_t)(nb + r + 0) * 64 + lane] = f2bf(a0);
        Y[(size_t)(nb + r + 1) * 64 + lane] = f2bf(a1);
        Y[(size_t)(nb + r + 2) * 64 + lane] = f2bf(a2);
        Y[(size_t)(nb + r + 3) * 64 + lane] = f2bf(a3);
        __syncthreads();
    }
}

// ---------------- gather: T[i](bf16) = relu(Y[i] + bias + sum_{e} Y[src[e]]) ----------------
// R4-proven structure: one wave per node, 25K blocks (max parallelism)
__global__ __launch_bounds__(256) void gather_kernel(const unsigned short* __restrict__ Y,
                                                     const int* __restrict__ row_ptr,
                                                     const int* __restrict__ esrc,
                                                     const float* __restrict__ bias,
                                                     unsigned short* __restrict__ T, int N) {
    int wv = threadIdx.x >> 6, lane = threadIdx.x & 63;
    int node = blockIdx.x * 4 + wv;
    if (node >= N) return;
    float acc = bf2f(Y[(size_t)node * 64 + lane]) + bias[lane];
    int e0 = row_ptr[node], e1 = row_ptr[node + 1];
    int e = e0;
    for (; e + 8 <= e1; e += 8) {
        int s0 = __builtin_nontemporal_load(&esrc[e]);
        int s1 = __builtin_nontemporal_load(&esrc[e + 1]);
        int s2 = __builtin_nontemporal_load(&esrc[e + 2]);
        int s3 = __builtin_nontemporal_load(&esrc[e + 3]);
        int s4 = __builtin_nontemporal_load(&esrc[e + 4]);
        int s5 = __builtin_nontemporal_load(&esrc[e + 5]);
        int s6 = __builtin_nontemporal_load(&esrc[e + 6]);
        int s7 = __builtin_nontemporal_load(&esrc[e + 7]);
        float f0 = bf2f(Y[(size_t)s0 * 64 + lane]);
        float f1 = bf2f(Y[(size_t)s1 * 64 + lane]);
        float f2 = bf2f(Y[(size_t)s2 * 64 + lane]);
        float f3 = bf2f(Y[(size_t)s3 * 64 + lane]);
        float f4 = bf2f(Y[(size_t)s4 * 64 + lane]);
        float f5 = bf2f(Y[(size_t)s5 * 64 + lane]);
        float f6 = bf2f(Y[(size_t)s6 * 64 + lane]);
        float f7 = bf2f(Y[(size_t)s7 * 64 + lane]);
        acc += ((f0 + f1) + (f2 + f3)) + ((f4 + f5) + (f6 + f7));
    }
    for (; e < e1; e++) acc += bf2f(Y[(size_t)__builtin_nontemporal_load(&esrc[e]) * 64 + lane]);
    __builtin_nontemporal_store(f2bf(fmaxf(acc, 0.f)), &T[(size_t)node * 64 + lane]);
}

// stage 16 nodes x 64 feats of bf16 into f32 LDS tile
__device__ __forceinline__ void stage_bf16_tile(const unsigned short* __restrict__ src,
                                                float* __restrict__ dst, int tid) {
    const ushort4* s4 = (const ushort4*)src;
    ushort4 u = s4[tid];  // 256 threads x 4 elems = 1024
    float4* d4 = (float4*)dst;
    d4[tid] = make_float4(bf2f(u.x), bf2f(u.y), bf2f(u.z), bf2f(u.w));
}

// ---------------- fused: Y(bf16) = (relu(bn(T@W1^T + b1))) @ W2^T ----------------
__global__ __launch_bounds__(256) void fused_mlp2_kernel(
    const unsigned short* __restrict__ T, const float* __restrict__ W1,
    const float* __restrict__ b1, const float* __restrict__ g, const float* __restrict__ be,
    const float* __restrict__ m, const float* __restrict__ v, const float* __restrict__ W2,
    unsigned short* __restrict__ Y, int N) {
    __shared__ float w1lds[64 * 64];
    __shared__ float w2lds[64 * 64];
    __shared__ float tl[16 * 64];
    __shared__ float hl[16 * 64];
    int tid = threadIdx.x, wv = tid >> 6, lane = tid & 63;
    for (int j = tid; j < 4096; j += 256) {
        int o = j >> 6, k = j & 63;
        int idx = (k >> 2) * 256 + o * 4 + (k & 3);
        w1lds[idx] = W1[j];
        w2lds[idx] = W2[j];
    }
    float bias = b1[lane];
    float s = g[lane] * rsqrtf(v[lane] + BN_EPS);
    float c = be[lane] - m[lane] * s;
    __syncthreads();
    const float4* w14 = (const float4*)w1lds;
    const float4* w24 = (const float4*)w2lds;
    const float4* t4 = (const float4*)tl;
    const float4* h4 = (const float4*)hl;
    for (int nb = blockIdx.x * 16; nb < N; nb += gridDim.x * 16) {
        stage_bf16_tile(T + (size_t)nb * 64, tl, tid);
        __syncthreads();
        int r = wv * 4;
        float a0 = bias, a1 = bias, a2 = bias, a3 = bias;
#pragma unroll
        for (int kb = 0; kb < 16; kb++) {
            float4 w = w14[kb * 64 + lane];
            float4 x0 = t4[(r + 0) * 16 + kb];
            float4 x1 = t4[(r + 1) * 16 + kb];
            float4 x2 = t4[(r + 2) * 16 + kb];
            float4 x3 = t4[(r + 3) * 16 + kb];
            a0 += x0.x * w.x + x0.y * w.y + x0.z * w.z + x0.w * w.w;
            a1 += x1.x * w.x + x1.y * w.y + x1.z * w.z + x1.w * w.w;
            a2 += x2.x * w.x + x2.y * w.y + x2.z * w.z + x2.w * w.w;
            a3 += x3.x * w.x + x3.y * w.y + x3.z * w.z + x3.w * w.w;
        }
        a0 = fmaxf(a0 * s + c, 0.f);
        a1 = fmaxf(a1 * s + c, 0.f);
        a2 = fmaxf(a2 * s + c, 0.f);
        a3 = fmaxf(a3 * s + c, 0.f);
        hl[(r + 0) * 64 + lane] = a0;
        hl[(r + 1) * 64 + lane] = a1;
        hl[(r + 2) * 64 + lane] = a2;
        hl[(r + 3) * 64 + lane] = a3;
        __syncthreads();
        float o0 = 0.f, o1 = 0.f, o2 = 0.f, o3 = 0.f;
#pragma unroll
        for (int kb = 0; kb < 16; kb++) {
            float4 w = w24[kb * 64 + lane];
            float4 x0 = h4[(r + 0) * 16 + kb];
            float4 x1 = h4[(r + 1) * 16 + kb];
            float4 x2 = h4[(r + 2) * 16 + kb];
            float4 x3 = h4[(r + 3) * 16 + kb];
            o0 += x0.x * w.x + x0.y * w.y + x0.z * w.z + x0.w * w.w;
            o1 += x1.x * w.x + x1.y * w.y + x1.z * w.z + x1.w * w.w;
            o2 += x2.x * w.x + x2.y * w.y + x2.z * w.z + x2.w * w.w;
            o3 += x3.x * w.x + x3.y * w.y + x3.z * w.z + x3.w * w.w;
        }
        Y[(size_t)(nb + r + 0) * 64 + lane] = f2bf(o0);
        Y[(size_t)(nb + r + 1) * 64 + lane] = f2bf(o1);
        Y[(size_t)(nb + r + 2) * 64 + lane] = f2bf(o2);
        Y[(size_t)(nb + r + 3) * 64 + lane] = f2bf(o3);
        __syncthreads();
    }
}

// ---------------- fused: relu(bn(T@W^T + b)) -> atomic mean-pool accumulate ----------------
// H never touches HBM: each row is atomically added into out[graph] (128KB, L2-resident).
__global__ __launch_bounds__(256) void fused_mlp1_pool_kernel(
    const unsigned short* __restrict__ T, const float* __restrict__ W,
    const float* __restrict__ b, const float* __restrict__ g, const float* __restrict__ be,
    const float* __restrict__ m, const float* __restrict__ v,
    const int* __restrict__ batch, float* __restrict__ out, int N) {
    __shared__ float wlds[64 * 64];
    __shared__ float tl[16 * 64];
    int tid = threadIdx.x, wv = tid >> 6, lane = tid & 63;
    for (int j = tid; j < 4096; j += 256) {
        int o = j >> 6, k = j & 63;
        wlds[(k >> 2) * 256 + o * 4 + (k & 3)] = W[j];
    }
    float bias = b[lane];
    float s = g[lane] * rsqrtf(v[lane] + BN_EPS);
    float c = be[lane] - m[lane] * s;
    __syncthreads();
    const float4* w4 = (const float4*)wlds;
    const float4* t4 = (const float4*)tl;
    for (int nb = blockIdx.x * 16; nb < N; nb += gridDim.x * 16) {
        stage_bf16_tile(T + (size_t)nb * 64, tl, tid);
        __syncthreads();
        int r = wv * 4;
        float a0 = bias, a1 = bias, a2 = bias, a3 = bias;
#pragma unroll
        for (int kb = 0; kb < 16; kb++) {
            float4 w = w4[kb * 64 + lane];
            float4 x0 = t4[(r + 0) * 16 + kb];
            float4 x1 = t4[(r + 1) * 16 + kb];
            float4 x2 = t4[(r + 2) * 16 + kb];
            float4 x3 = t4[(r + 3) * 16 + kb];
            a0 += x0.x * w.x + x0.y * w.y + x0.z * w.z + x0.w * w.w;
            a1 += x1.x * w.x + x1.y * w.y + x1.z * w.z + x1.w * w.w;
            a2 += x2.x * w.x + x2.y * w.y + x2.z * w.z + x2.w * w.w;
            a3 += x3.x * w.x + x3.y * w.y + x3.z * w.z + x3.w * w.w;
        }
        a0 = fmaxf(a0 * s + c, 0.f);
        a1 = fmaxf(a1 * s + c, 0.f);
        a2 = fmaxf(a2 * s + c, 0.f);
        a3 = fmaxf(a3 * s + c, 0.f);
        int n0 = nb + r;
        if (n0 + 0 < N) atomicAdd(&out[(size_t)batch[n0 + 0] * 64 + lane], a0);
        if (n0 + 1 < N) atomicAdd(&out[(size_t)batch[n0 + 1] * 64 + lane], a1);
        if (n0 + 2 < N) atomicAdd(&out[(size_t)batch[n0 + 2] * 64 + lane], a2);
        if (n0 + 3 < N) atomicAdd(&out[(size_t)batch[n0 + 3] * 64 + lane], a3);
        __syncthreads();
    }
}

// finalize mean: out[g] /= count(g) via binary search on sorted batch
__global__ __launch_bounds__(64) void divide_kernel(const int* __restrict__ batch,
                                                    float* __restrict__ out, int N) {
    int g = blockIdx.x, t = threadIdx.x;
    int lo = 0, hi = N;
    while (lo < hi) { int mid = (lo + hi) >> 1; if (batch[mid] < g) lo = mid + 1; else hi = mid; }
    int start = lo;
    hi = N;
    while (lo < hi) { int mid = (lo + hi) >> 1; if (batch[mid] < g + 1) lo = mid + 1; else hi = mid; }
    float inv = 1.0f / fmaxf((float)(lo - start), 1.0f);
    out[(size_t)g * 64 + t] *= inv;
}

extern "C" void kernel_launch(void* const* d_in, const int* in_sizes, int n_in,
                              void* d_out, int out_size, void* d_ws, size_t ws_size,
                              hipStream_t stream) {
    const float* x   = (const float*)d_in[0];
    const int*   ei  = (const int*)d_in[1];
    const int*   bat = (const int*)d_in[2];
    const float* W1a = (const float*)d_in[3];
    const float* b1a = (const float*)d_in[4];
    const float* W1b = (const float*)d_in[5];
    const float* b1b = (const float*)d_in[6];
    const float* g1  = (const float*)d_in[7];
    const float* be1 = (const float*)d_in[8];
    const float* m1  = (const float*)d_in[9];
    const float* v1  = (const float*)d_in[10];
    const float* W2a = (const float*)d_in[11];
    const float* b2a = (const float*)d_in[12];
    const float* W2b = (const float*)d_in[13];
    const float* b2b = (const float*)d_in[14];
    const float* g2  = (const float*)d_in[15];
    const float* be2 = (const float*)d_in[16];
    const float* m2  = (const float*)d_in[17];
    const float* v2  = (const float*)d_in[18];
    float* out = (float*)d_out;

    int N = in_sizes[0] / 128;
    int E = in_sizes[1] / 2;
    int G = out_size / 64;
    int nbuck = (N + 255) >> 8;
    int ntile = (N + 15) / 16;

    // workspace layout
    char* ws = (char*)d_ws;
    int* row_ptr = (int*)ws;                              // N+1 (padded)
    int* bcnt = row_ptr + ((N + 1 + 3) & ~3);             // MAXB
    int* boff = bcnt + MAXB;                              // MAXB+4
    int* bpos = boff + MAXB + 4;                          // MAXB
    int* esrc = bpos + MAXB;                              // E
    unsigned short* bufA = (unsigned short*)(esrc + E);   // N*64 bf16
    unsigned short* bufB = bufA + (size_t)N * 64;         // N*64 bf16
    int* binned = (int*)bufB;                             // aliases bufB (dead until gather#1)

    // CSR build
    hipMemsetAsync(bcnt, 0, MAXB * sizeof(int), stream);
    bin_count<<<512, 256, 0, stream>>>(ei, E, bcnt, nbuck);
    scan_small<<<1, 512, 0, stream>>>(bcnt, boff, bpos, row_ptr + N, nbuck, E);
    bin_scatter<<<(E + CHUNK - 1) / CHUNK, 256, 0, stream>>>(ei, E, bpos, binned, nbuck);
    bucket_csr<<<nbuck, 512, 0, stream>>>(binned, boff, row_ptr, esrc, N);

    // layer 1
    linear_kernel<128><<<ntile, 256, 0, stream>>>(x, W1a, bufA, N);
    gather_kernel<<<(N + 3) / 4, 256, 0, stream>>>(bufA, row_ptr, esrc, b1a, bufB, N);
    fused_mlp2_kernel<<<ntile, 256, 0, stream>>>(bufB, W1b, b1b, g1, be1, m1, v1, W2a, bufA, N);

    // layer 2: gather, then mlp1 fused with atomic mean-pool (H never hits HBM)
    gather_kernel<<<(N + 3) / 4, 256, 0, stream>>>(bufA, row_ptr, esrc, b2a, bufB, N);
    hipMemsetAsync(out, 0, (size_t)out_size * sizeof(float), stream);
    fused_mlp1_pool_kernel<<<ntile, 256, 0, stream>>>(bufB, W2b, b2b, g2, be2, m2, v2, bat, out, N);
    divide_kernel<<<G, 64, 0, stream>>>(bat, out, N);
}

// Round 8
// 449.383 us; speedup vs baseline: 3.7827x; 1.2823x over previous
//
#include <hip/hip_runtime.h>

#define BN_EPS 1e-5f
#define CHUNK 4096
#define MAXB 512  // max buckets (N up to 131072 with 256 nodes/bucket)

// bf16 helpers (RNE pack, cheap unpack)
__device__ __forceinline__ unsigned short f2bf(float f) {
    unsigned int u = __float_as_uint(f);
    u += 0x7FFF + ((u >> 16) & 1);
    return (unsigned short)(u >> 16);
}
__device__ __forceinline__ float bf2f(unsigned short h) {
    return __uint_as_float((unsigned int)h << 16);
}

// ---------------- CSR build: bucketed, no global random scatter ----------------

__global__ __launch_bounds__(256) void bin_count(const int* __restrict__ ei, int E,
                                                 int* __restrict__ bcnt, int nbuck) {
    __shared__ int h[MAXB];
    for (int i = threadIdx.x; i < nbuck; i += 256) h[i] = 0;
    __syncthreads();
    int i = blockIdx.x * 256 + threadIdx.x, stride = gridDim.x * 256;
    for (int e = i; e < E; e += stride) {
        int d = ei[E + e];
        atomicAdd(&h[d >> 8], 1);
    }
    __syncthreads();
    for (int b = threadIdx.x; b < nbuck; b += 256)
        if (h[b]) atomicAdd(&bcnt[b], h[b]);
}

__global__ __launch_bounds__(512) void scan_small(const int* __restrict__ bcnt,
                                                  int* __restrict__ boff,
                                                  int* __restrict__ bpos,
                                                  int* __restrict__ row_ptr_end,
                                                  int nbuck, int E) {
    __shared__ int wsum[8];
    int tid = threadIdx.x, lane = tid & 63, wv = tid >> 6;
    int val = (tid < nbuck) ? bcnt[tid] : 0;
    int s = val;
#pragma unroll
    for (int off = 1; off < 64; off <<= 1) {
        int t = __shfl_up(s, off, 64);
        if (lane >= off) s += t;
    }
    if (lane == 63) wsum[wv] = s;
    __syncthreads();
    if (wv == 0) {
        int t = (lane < 8) ? wsum[lane] : 0;
#pragma unroll
        for (int off = 1; off < 8; off <<= 1) {
            int u = __shfl_up(t, off, 64);
            if (lane >= off) t += u;
        }
        if (lane < 8) wsum[lane] = t;
    }
    __syncthreads();
    int excl = ((wv == 0) ? 0 : wsum[wv - 1]) + s - val;
    if (tid < nbuck) { boff[tid] = excl; bpos[tid] = excl; }
    if (tid == 0) { boff[nbuck] = E; *row_ptr_end = E; }
}

// 4K-edge chunks -> 391 blocks (2x the R4 parallelism; per-bucket runs ~10 edges
// => binned write-amp ~1.6x =~10MB, acceptable; avoids the 196-block thinness)
__global__ __launch_bounds__(256) void bin_scatter(const int* __restrict__ ei, int E,
                                                   int* __restrict__ bpos,
                                                   int* __restrict__ binned, int nbuck) {
    __shared__ int h[MAXB];
    __shared__ int res[MAXB];
    int base = blockIdx.x * CHUNK;
    int cnt = min(CHUNK, E - base);
    int tid = threadIdx.x;
    for (int b = tid; b < nbuck; b += 256) h[b] = 0;
    __syncthreads();
    for (int k = tid; k < cnt; k += 256) {
        int d = ei[E + base + k];
        atomicAdd(&h[d >> 8], 1);
    }
    __syncthreads();
    for (int b = tid; b < nbuck; b += 256) {
        int c = h[b];
        res[b] = c ? atomicAdd(&bpos[b], c) : 0;
        h[b] = 0;  // reuse as rank counter
    }
    __syncthreads();
    for (int k = tid; k < cnt; k += 256) {
        int srcv = ei[base + k];
        int d = ei[E + base + k];
        int b = d >> 8;
        int r = atomicAdd(&h[b], 1);
        binned[res[b] + r] = ((d & 255) << 17) | srcv;  // src < 2^17
    }
}

// one workgroup per 256-node bucket (R4-proven): counts -> scan -> row_ptr + ranked esrc
__global__ __launch_bounds__(256) void bucket_csr(const int* __restrict__ binned,
                                                  const int* __restrict__ boff,
                                                  int* __restrict__ row_ptr,
                                                  int* __restrict__ esrc, int N) {
    __shared__ int ncnt[256];
    __shared__ int npos[256];
    __shared__ int wsum[4];
    int b = blockIdx.x, tid = threadIdx.x, lane = tid & 63, wv = tid >> 6;
    int lo = boff[b], hi = boff[b + 1];
    int base_node = b << 8;
    ncnt[tid] = 0;
    __syncthreads();
    for (int i = lo + tid; i < hi; i += 256)
        atomicAdd(&ncnt[binned[i] >> 17], 1);
    __syncthreads();
    int c = ncnt[tid];
    int s = c;
#pragma unroll
    for (int off = 1; off < 64; off <<= 1) {
        int t = __shfl_up(s, off, 64);
        if (lane >= off) s += t;
    }
    if (lane == 63) wsum[wv] = s;
    __syncthreads();
    int woff = 0;
#pragma unroll
    for (int i = 0; i < 4; i++) woff += (i < wv) ? wsum[i] : 0;
    int abspos = lo + woff + (s - c);
    if (base_node + tid < N) row_ptr[base_node + tid] = abspos;
    npos[tid] = abspos;
    __syncthreads();
    for (int i = lo + tid; i < hi; i += 256) {
        int val = binned[i];
        int r = atomicAdd(&npos[val >> 17], 1);
        esrc[r] = val & 0x1FFFF;
    }
}

// ---------------- dense: Y[n][64](bf16) = X[n][K](f32) @ W[64][K]^T ----------------
template <int K>
__global__ __launch_bounds__(256) void linear_kernel(const float* __restrict__ X,
                                                     const float* __restrict__ W,
                                                     unsigned short* __restrict__ Y, int N) {
    __shared__ float wlds[K * 64];
    __shared__ float xlds[16 * K];
    int tid = threadIdx.x;
    for (int j = tid; j < 64 * K; j += 256) {
        int o = j / K, k = j % K;
        wlds[(k >> 2) * 256 + o * 4 + (k & 3)] = W[j];
    }
    __syncthreads();
    const float4* w4p = (const float4*)wlds;
    const float4* x4p = (const float4*)xlds;
    int wv = tid >> 6, lane = tid & 63;
    for (int nb = blockIdx.x * 16; nb < N; nb += gridDim.x * 16) {
        const float4* xg = (const float4*)(X + (size_t)nb * K);
        float4* xl = (float4*)xlds;
        for (int j = tid; j < 16 * K / 4; j += 256) xl[j] = xg[j];
        __syncthreads();
        int r = wv * 4;
        float a0 = 0.f, a1 = 0.f, a2 = 0.f, a3 = 0.f;
#pragma unroll 8
        for (int kb = 0; kb < K / 4; kb++) {
            float4 w = w4p[kb * 64 + lane];
            float4 x0 = x4p[(r + 0) * (K / 4) + kb];
            float4 x1 = x4p[(r + 1) * (K / 4) + kb];
            float4 x2 = x4p[(r + 2) * (K / 4) + kb];
            float4 x3 = x4p[(r + 3) * (K / 4) + kb];
            a0 += x0.x * w.x + x0.y * w.y + x0.z * w.z + x0.w * w.w;
            a1 += x1.x * w.x + x1.y * w.y + x1.z * w.z + x1.w * w.w;
            a2 += x2.x * w.x + x2.y * w.y + x2.z * w.z + x2.w * w.w;
            a3 += x3.x * w.x + x3.y * w.y + x3.z * w.z + x3.w * w.w;
        }
        Y[(size_t)(nb + r + 0) * 64 + lane] = f2bf(a0);
        Y[(size_t)(nb + r + 1) * 64 + lane] = f2bf(a1);
        Y[(size_t)(nb + r + 2) * 64 + lane] = f2bf(a2);
        Y[(size_t)(nb + r + 3) * 64 + lane] = f2bf(a3);
        __syncthreads();
    }
}

// ---------------- gather: T[i](bf16) = relu(Y[i] + bias + sum_{e} Y[src[e]]) ----------------
// R4-proven exactly: one wave per node, 25K blocks, plain loads/stores
__global__ __launch_bounds__(256) void gather_kernel(const unsigned short* __restrict__ Y,
                                                     const int* __restrict__ row_ptr,
                                                     const int* __restrict__ esrc,
                                                     const float* __restrict__ bias,
                                                     unsigned short* __restrict__ T, int N) {
    int wv = threadIdx.x >> 6, lane = threadIdx.x & 63;
    int node = blockIdx.x * 4 + wv;
    if (node >= N) return;
    float acc = bf2f(Y[(size_t)node * 64 + lane]) + bias[lane];
    int e0 = row_ptr[node], e1 = row_ptr[node + 1];
    int e = e0;
    for (; e + 8 <= e1; e += 8) {
        int s0 = esrc[e], s1 = esrc[e + 1], s2 = esrc[e + 2], s3 = esrc[e + 3];
        int s4 = esrc[e + 4], s5 = esrc[e + 5], s6 = esrc[e + 6], s7 = esrc[e + 7];
        float f0 = bf2f(Y[(size_t)s0 * 64 + lane]);
        float f1 = bf2f(Y[(size_t)s1 * 64 + lane]);
        float f2 = bf2f(Y[(size_t)s2 * 64 + lane]);
        float f3 = bf2f(Y[(size_t)s3 * 64 + lane]);
        float f4 = bf2f(Y[(size_t)s4 * 64 + lane]);
        float f5 = bf2f(Y[(size_t)s5 * 64 + lane]);
        float f6 = bf2f(Y[(size_t)s6 * 64 + lane]);
        float f7 = bf2f(Y[(size_t)s7 * 64 + lane]);
        acc += ((f0 + f1) + (f2 + f3)) + ((f4 + f5) + (f6 + f7));
    }
    for (; e < e1; e++) acc += bf2f(Y[(size_t)esrc[e] * 64 + lane]);
    T[(size_t)node * 64 + lane] = f2bf(fmaxf(acc, 0.f));
}

// stage 16 nodes x 64 feats of bf16 into f32 LDS tile
__device__ __forceinline__ void stage_bf16_tile(const unsigned short* __restrict__ src,
                                                float* __restrict__ dst, int tid) {
    const ushort4* s4 = (const ushort4*)src;
    ushort4 u = s4[tid];  // 256 threads x 4 elems = 1024
    float4* d4 = (float4*)dst;
    d4[tid] = make_float4(bf2f(u.x), bf2f(u.y), bf2f(u.z), bf2f(u.w));
}

// ---------------- fused: Y(bf16) = (relu(bn(T@W1^T + b1))) @ W2^T ----------------
__global__ __launch_bounds__(256) void fused_mlp2_kernel(
    const unsigned short* __restrict__ T, const float* __restrict__ W1,
    const float* __restrict__ b1, const float* __restrict__ g, const float* __restrict__ be,
    const float* __restrict__ m, const float* __restrict__ v, const float* __restrict__ W2,
    unsigned short* __restrict__ Y, int N) {
    __shared__ float w1lds[64 * 64];
    __shared__ float w2lds[64 * 64];
    __shared__ float tl[16 * 64];
    __shared__ float hl[16 * 64];
    int tid = threadIdx.x, wv = tid >> 6, lane = tid & 63;
    for (int j = tid; j < 4096; j += 256) {
        int o = j >> 6, k = j & 63;
        int idx = (k >> 2) * 256 + o * 4 + (k & 3);
        w1lds[idx] = W1[j];
        w2lds[idx] = W2[j];
    }
    float bias = b1[lane];
    float s = g[lane] * rsqrtf(v[lane] + BN_EPS);
    float c = be[lane] - m[lane] * s;
    __syncthreads();
    const float4* w14 = (const float4*)w1lds;
    const float4* w24 = (const float4*)w2lds;
    const float4* t4 = (const float4*)tl;
    const float4* h4 = (const float4*)hl;
    for (int nb = blockIdx.x * 16; nb < N; nb += gridDim.x * 16) {
        stage_bf16_tile(T + (size_t)nb * 64, tl, tid);
        __syncthreads();
        int r = wv * 4;
        float a0 = bias, a1 = bias, a2 = bias, a3 = bias;
#pragma unroll
        for (int kb = 0; kb < 16; kb++) {
            float4 w = w14[kb * 64 + lane];
            float4 x0 = t4[(r + 0) * 16 + kb];
            float4 x1 = t4[(r + 1) * 16 + kb];
            float4 x2 = t4[(r + 2) * 16 + kb];
            float4 x3 = t4[(r + 3) * 16 + kb];
            a0 += x0.x * w.x + x0.y * w.y + x0.z * w.z + x0.w * w.w;
            a1 += x1.x * w.x + x1.y * w.y + x1.z * w.z + x1.w * w.w;
            a2 += x2.x * w.x + x2.y * w.y + x2.z * w.z + x2.w * w.w;
            a3 += x3.x * w.x + x3.y * w.y + x3.z * w.z + x3.w * w.w;
        }
        a0 = fmaxf(a0 * s + c, 0.f);
        a1 = fmaxf(a1 * s + c, 0.f);
        a2 = fmaxf(a2 * s + c, 0.f);
        a3 = fmaxf(a3 * s + c, 0.f);
        hl[(r + 0) * 64 + lane] = a0;
        hl[(r + 1) * 64 + lane] = a1;
        hl[(r + 2) * 64 + lane] = a2;
        hl[(r + 3) * 64 + lane] = a3;
        __syncthreads();
        float o0 = 0.f, o1 = 0.f, o2 = 0.f, o3 = 0.f;
#pragma unroll
        for (int kb = 0; kb < 16; kb++) {
            float4 w = w24[kb * 64 + lane];
            float4 x0 = h4[(r + 0) * 16 + kb];
            float4 x1 = h4[(r + 1) * 16 + kb];
            float4 x2 = h4[(r + 2) * 16 + kb];
            float4 x3 = h4[(r + 3) * 16 + kb];
            o0 += x0.x * w.x + x0.y * w.y + x0.z * w.z + x0.w * w.w;
            o1 += x1.x * w.x + x1.y * w.y + x1.z * w.z + x1.w * w.w;
            o2 += x2.x * w.x + x2.y * w.y + x2.z * w.z + x2.w * w.w;
            o3 += x3.x * w.x + x3.y * w.y + x3.z * w.z + x3.w * w.w;
        }
        Y[(size_t)(nb + r + 0) * 64 + lane] = f2bf(o0);
        Y[(size_t)(nb + r + 1) * 64 + lane] = f2bf(o1);
        Y[(size_t)(nb + r + 2) * 64 + lane] = f2bf(o2);
        Y[(size_t)(nb + r + 3) * 64 + lane] = f2bf(o3);
        __syncthreads();
    }
}

// ---------------- H(bf16) = relu(bn(T@W^T + b)) ----------------
__global__ __launch_bounds__(256) void fused_mlp1_kernel(
    const unsigned short* __restrict__ T, const float* __restrict__ W,
    const float* __restrict__ b, const float* __restrict__ g, const float* __restrict__ be,
    const float* __restrict__ m, const float* __restrict__ v,
    unsigned short* __restrict__ H, int N) {
    __shared__ float wlds[64 * 64];
    __shared__ float tl[16 * 64];
    int tid = threadIdx.x, wv = tid >> 6, lane = tid & 63;
    for (int j = tid; j < 4096; j += 256) {
        int o = j >> 6, k = j & 63;
        wlds[(k >> 2) * 256 + o * 4 + (k & 3)] = W[j];
    }
    float bias = b[lane];
    float s = g[lane] * rsqrtf(v[lane] + BN_EPS);
    float c = be[lane] - m[lane] * s;
    __syncthreads();
    const float4* w4 = (const float4*)wlds;
    const float4* t4 = (const float4*)tl;
    for (int nb = blockIdx.x * 16; nb < N; nb += gridDim.x * 16) {
        stage_bf16_tile(T + (size_t)nb * 64, tl, tid);
        __syncthreads();
        int r = wv * 4;
        float a0 = bias, a1 = bias, a2 = bias, a3 = bias;
#pragma unroll
        for (int kb = 0; kb < 16; kb++) {
            float4 w = w4[kb * 64 + lane];
            float4 x0 = t4[(r + 0) * 16 + kb];
            float4 x1 = t4[(r + 1) * 16 + kb];
            float4 x2 = t4[(r + 2) * 16 + kb];
            float4 x3 = t4[(r + 3) * 16 + kb];
            a0 += x0.x * w.x + x0.y * w.y + x0.z * w.z + x0.w * w.w;
            a1 += x1.x * w.x + x1.y * w.y + x1.z * w.z + x1.w * w.w;
            a2 += x2.x * w.x + x2.y * w.y + x2.z * w.z + x2.w * w.w;
            a3 += x3.x * w.x + x3.y * w.y + x3.z * w.z + x3.w * w.w;
        }
        H[(size_t)(nb + r + 0) * 64 + lane] = f2bf(fmaxf(a0 * s + c, 0.f));
        H[(size_t)(nb + r + 1) * 64 + lane] = f2bf(fmaxf(a1 * s + c, 0.f));
        H[(size_t)(nb + r + 2) * 64 + lane] = f2bf(fmaxf(a2 * s + c, 0.f));
        H[(size_t)(nb + r + 3) * 64 + lane] = f2bf(fmaxf(a3 * s + c, 0.f));
        __syncthreads();
    }
}

// ---------------- mean pool per graph (batch is sorted) ----------------
__global__ __launch_bounds__(256) void pool_kernel(const unsigned short* __restrict__ H,
                                                   const int* __restrict__ batch,
                                                   float* __restrict__ out, int N) {
    __shared__ float part[4][64];
    int g = blockIdx.x;
    int tid = threadIdx.x, wv = tid >> 6, lane = tid & 63;
    int lo = 0, hi = N;
    while (lo < hi) { int mid = (lo + hi) >> 1; if (batch[mid] < g) lo = mid + 1; else hi = mid; }
    int start = lo;
    hi = N;
    while (lo < hi) { int mid = (lo + hi) >> 1; if (batch[mid] < g + 1) lo = mid + 1; else hi = mid; }
    int end = lo;
    float acc = 0.f;
    for (int i = start + wv; i < end; i += 4) acc += bf2f(H[(size_t)i * 64 + lane]);
    part[wv][lane] = acc;
    __syncthreads();
    if (tid < 64) {
        float sfin = part[0][tid] + part[1][tid] + part[2][tid] + part[3][tid];
        float cnt = (float)(end - start);
        out[(size_t)g * 64 + tid] = sfin / fmaxf(cnt, 1.f);
    }
}

extern "C" void kernel_launch(void* const* d_in, const int* in_sizes, int n_in,
                              void* d_out, int out_size, void* d_ws, size_t ws_size,
                              hipStream_t stream) {
    const float* x   = (const float*)d_in[0];
    const int*   ei  = (const int*)d_in[1];
    const int*   bat = (const int*)d_in[2];
    const float* W1a = (const float*)d_in[3];
    const float* b1a = (const float*)d_in[4];
    const float* W1b = (const float*)d_in[5];
    const float* b1b = (const float*)d_in[6];
    const float* g1  = (const float*)d_in[7];
    const float* be1 = (const float*)d_in[8];
    const float* m1  = (const float*)d_in[9];
    const float* v1  = (const float*)d_in[10];
    const float* W2a = (const float*)d_in[11];
    const float* b2a = (const float*)d_in[12];
    const float* W2b = (const float*)d_in[13];
    const float* b2b = (const float*)d_in[14];
    const float* g2  = (const float*)d_in[15];
    const float* be2 = (const float*)d_in[16];
    const float* m2  = (const float*)d_in[17];
    const float* v2  = (const float*)d_in[18];
    float* out = (float*)d_out;

    int N = in_sizes[0] / 128;
    int E = in_sizes[1] / 2;
    int G = out_size / 64;
    int nbuck = (N + 255) >> 8;

    // workspace layout (bf16 feature buffers)
    char* ws = (char*)d_ws;
    int* row_ptr = (int*)ws;                              // N+1 (padded)
    int* bcnt = row_ptr + ((N + 1 + 3) & ~3);             // MAXB
    int* boff = bcnt + MAXB;                              // MAXB+1
    int* bpos = boff + MAXB + 4;                          // MAXB
    int* esrc = bpos + MAXB;                              // E
    unsigned short* bufA = (unsigned short*)(esrc + E);   // N*64 bf16
    unsigned short* bufB = bufA + (size_t)N * 64;         // N*64 bf16
    int* binned = (int*)bufB;                             // aliases bufB (dead until gather#1)

    // CSR build
    hipMemsetAsync(bcnt, 0, MAXB * sizeof(int), stream);
    bin_count<<<512, 256, 0, stream>>>(ei, E, bcnt, nbuck);
    scan_small<<<1, 512, 0, stream>>>(bcnt, boff, bpos, row_ptr + N, nbuck, E);
    bin_scatter<<<(E + CHUNK - 1) / CHUNK, 256, 0, stream>>>(ei, E, bpos, binned, nbuck);
    bucket_csr<<<nbuck, 256, 0, stream>>>(binned, boff, row_ptr, esrc, N);

    // layer 1
    linear_kernel<128><<<2048, 256, 0, stream>>>(x, W1a, bufA, N);
    gather_kernel<<<(N + 3) / 4, 256, 0, stream>>>(bufA, row_ptr, esrc, b1a, bufB, N);
    fused_mlp2_kernel<<<2048, 256, 0, stream>>>(bufB, W1b, b1b, g1, be1, m1, v1, W2a, bufA, N);

    // layer 2
    gather_kernel<<<(N + 3) / 4, 256, 0, stream>>>(bufA, row_ptr, esrc, b2a, bufB, N);
    fused_mlp1_kernel<<<2048, 256, 0, stream>>>(bufB, W2b, b2b, g2, be2, m2, v2, bufA, N);

    // mean pool
    pool_kernel<<<G, 256, 0, stream>>>(bufA, bat, out, N);
}